// Round 11
// baseline (201.542 us; speedup 1.0000x reference)
//
#include <hip/hip_runtime.h>
#include <math.h>
#include <stdint.h>

#define T_STEPS 256
#define BS      512
#define N       2048
#define BLOCK   256               // 4 waves per batch element, EPT=8
#define FUDGE   1e-4f

// R18 (resubmit; infra failed before execution): two fixes on R17 (121us).
//  (1) Scalar prefetch moved OFF lgkmcnt: per-step y/q/nz now come via
//      uniform-address global_load_dword into VGPRs (vmcnt). In-loop
//      lgkmcnt(0) drains now see ONLY the ds_write/ds_read they order;
//      the loads are covered by one counted s_waitcnt vmcnt(1) placed
//      where they are ~1 iteration old (never stalls). R17 still exposed
//      ~50-150cy/step of SMEM latency at the pre-barrier drain. To keep
//      per-wave vmcnt arithmetic uniform, lane0 of ALL 4 waves stores the
//      (identical) output value -- benign duplicate store.
//  (2) Critical path shortened: qlp/qsc, hb=cb+qsc*cq, ylp, pre=ylp+nz',
//      elpre=lr0*lrm all computed in the ds_read shadow; post-exchange
//      chain is u -> x=fma(ufs-1,u,pre) -> h=fma(x,cw,hb). Dots use
//      pk_mul + add-tree (no zero-init, 2 fewer dependence levels).
__global__ __launch_bounds__(BLOCK, 2)
void legacy_elbo_scan_kernel(
    const float* __restrict__ noises,   // [T, BS]
    const float* __restrict__ ys,       // [T]
    const float* __restrict__ qs,       // [T]
    const float* __restrict__ z_biases, // [N]
    const float* __restrict__ w_in,     // [N]
    const float* __restrict__ w_inq,    // [N]
    const float* __restrict__ p_llr,
    const float* __restrict__ p_llrd,
    const float* __restrict__ p_sigb,
    const float* __restrict__ p_oscale,
    const float* __restrict__ p_ufs,
    const float* __restrict__ p_lwd,
    const float* __restrict__ p_qscale,
    const float* __restrict__ p_tauq,
    const float* __restrict__ p_tauy,
    float* __restrict__ out)            // [T, BS]
{
    const int tid = threadIdx.x;
    const int blk = blockIdx.x;

    __shared__ float red_lds[16];       // [parity 2][wave 4][su,sh] = 64 B
    if (tid < 16) red_lds[tid] = 0.0f;  // keep the allocation live, offset 0
    __syncthreads();

    const float sigb    = p_sigb[0];
    const float lr0     = expf(p_llr[0]);
    const float lr_decay= expf(p_llrd[0]);
    const float wd      = expf(p_lwd[0]);
    const float rwd     = 1.0f / wd;
    const float tauq    = 1.0f + log1pf(expf(p_tauq[0]));
    const float tauy    = 1.0f + log1pf(expf(p_tauy[0]));
    const float omtq    = 1.0f - tauq;
    const float omty    = 1.0f - tauy;
    const float qscale  = p_qscale[0];
    const float ufsm1   = p_ufs[0] - 1.0f;   // x = pre + (ufs-1)*u
    const float oscale  = p_oscale[0];
    // __expf(x) == exp2(x * log2(e)); fold -lr_decay into the multiplier.
    const float nld2    = -lr_decay * 1.4426950408889634f;

    const float* nzp = noises + blk;    // uniform: per-block noise column base
    const int    ovo = blk * 4;         // byte offset of out[0*BS+blk]

    asm volatile(
        // -------- init: ids, masks, LDS addrs, coeff + scalar loads ---------
        "v_lshrrev_b32 v3, 6, %[vtid]\n\t"          // wid (0..3)
        "v_lshlrev_b32 v4, 3, v3\n\t"               // ds write addr = wid*8
        "v_and_b32 v7, 63, %[vtid]\n\t"             // lane id
        "v_cmp_eq_u32 vcc, 63, v7\n\t"              // lane-63 mask
        "s_mov_b64 s[74:75], vcc\n\t"
        "v_cmp_eq_u32 vcc, 0, v7\n\t"               // lane-0 mask (ALL waves)
        "s_mov_b64 s[76:77], vcc\n\t"
        "v_mov_b32 v5, 0\n\t"                       // ds read base (parity 0)
        "v_lshlrev_b32 v1, 4, %[vtid]\n\t"          // tid*16 bytes
        "v_add_u32 v2, 0x1000, v1\n\t"              // +4096 for chunk 1
        "global_load_dwordx4 v[40:43], v1, %[pzb]\n\t"
        "global_load_dwordx4 v[44:47], v2, %[pzb]\n\t"
        "global_load_dwordx4 v[48:51], v1, %[pwi]\n\t"
        "global_load_dwordx4 v[52:55], v2, %[pwi]\n\t"
        "global_load_dwordx4 v[56:59], v1, %[pwq]\n\t"
        "global_load_dwordx4 v[60:63], v2, %[pwq]\n\t"
        // scalar triple-buffer A=t0(v96-98) B=t1(v99-101) C=t2(v102-104)
        "v_mov_b32 v105, 0\n\t"                     // y/q byte offset reg
        "v_mov_b32 v106, 0x1000\n\t"                // nz offset reg (t2)
        "global_load_dword v96,  v105, %[pys]\n\t"
        "global_load_dword v97,  v105, %[pqs]\n\t"
        "global_load_dword v98,  v105, %[pnz]\n\t"
        "global_load_dword v99,  v105, %[pys] offset:4\n\t"
        "global_load_dword v100, v105, %[pqs] offset:4\n\t"
        "global_load_dword v101, v105, %[pnz] offset:2048\n\t"
        "global_load_dword v102, v105, %[pys] offset:8\n\t"
        "global_load_dword v103, v105, %[pqs] offset:8\n\t"
        "global_load_dword v104, v106, %[pnz]\n\t"
        "v_mov_b32 v105, 12\n\t"                    // next issue = t3
        "v_mov_b32 v106, 0x1800\n\t"
        "s_waitcnt vmcnt(0)\n\t"
        // scale biases by sigma_b
        "v_mul_f32 v40, %[osg], v40\n\t"  "v_mul_f32 v41, %[osg], v41\n\t"
        "v_mul_f32 v42, %[osg], v42\n\t"  "v_mul_f32 v43, %[osg], v43\n\t"
        "v_mul_f32 v44, %[osg], v44\n\t"  "v_mul_f32 v45, %[osg], v45\n\t"
        "v_mul_f32 v46, %[osg], v46\n\t"  "v_mul_f32 v47, %[osg], v47\n\t"
        // zero w_out state v64..v71
        "v_mov_b32 v64, 0\n\t" "v_mov_b32 v65, 0\n\t" "v_mov_b32 v66, 0\n\t" "v_mov_b32 v67, 0\n\t"
        "v_mov_b32 v68, 0\n\t" "v_mov_b32 v69, 0\n\t" "v_mov_b32 v70, 0\n\t" "v_mov_b32 v71, 0\n\t"
        // state: qlp v20, ylp v21, u v22, lrm v24, sp v25, rsp v26
        "v_mov_b32 v21, 0\n\t" "v_mov_b32 v22, 0\n\t"
        "v_mov_b32 v24, 1.0\n\t" "v_mov_b32 v25, 1.0\n\t" "v_mov_b32 v26, 1.0\n\t"
        "v_mov_b32 v6, %[ovo]\n\t"                  // out byte-offset
        // qlp0 = tauq*q0 ; qsc0 pair v[10:11]
        "v_mul_f32 v20, %[otq], v97\n\t"
        "v_mul_f32 v10, %[oq], v20\n\t"
        "v_mov_b32 v11, v10\n\t"
        // hb0 = cb + qsc0*cq
        "v_pk_fma_f32 v[80:81], v[10:11], v[56:57], v[40:41]\n\t"
        "v_pk_fma_f32 v[82:83], v[10:11], v[58:59], v[42:43]\n\t"
        "v_pk_fma_f32 v[84:85], v[10:11], v[60:61], v[44:45]\n\t"
        "v_pk_fma_f32 v[86:87], v[10:11], v[62:63], v[46:47]\n\t"
        // x0 = nz0 (u=-0) ; pair v[8:9]
        "v_mov_b32 v8, v98\n\t"
        "v_mov_b32 v9, v8\n\t"
        "v_mov_b32 v27, %[olr]\n\t"                 // elpre0 = lr0*1
        "s_mov_b32 s60, 0\n\t"                      // t
        // ---------------- main scan loop ------------------------------------
        "Lelbo4:\n\t"
        // h = relu(hb + x*cw)
        "v_pk_fma_f32 v[72:73], v[8:9], v[48:49], v[80:81]\n\t"
        "v_pk_fma_f32 v[74:75], v[8:9], v[50:51], v[82:83]\n\t"
        "v_pk_fma_f32 v[76:77], v[8:9], v[52:53], v[84:85]\n\t"
        "v_pk_fma_f32 v[78:79], v[8:9], v[54:55], v[86:87]\n\t"
        "v_max_f32 v72, 0, v72\n\t" "v_max_f32 v73, 0, v73\n\t"
        "v_max_f32 v74, 0, v74\n\t" "v_max_f32 v75, 0, v75\n\t"
        "v_max_f32 v76, 0, v76\n\t" "v_max_f32 v77, 0, v77\n\t"
        "v_max_f32 v78, 0, v78\n\t" "v_max_f32 v79, 0, v79\n\t"
        // dot products: su = v.h (v12-19), sh = h.h (v88-95), tree-reduced
        "v_pk_mul_f32 v[12:13], v[64:65], v[72:73]\n\t"
        "v_pk_mul_f32 v[14:15], v[66:67], v[74:75]\n\t"
        "v_pk_mul_f32 v[16:17], v[68:69], v[76:77]\n\t"
        "v_pk_mul_f32 v[18:19], v[70:71], v[78:79]\n\t"
        "v_pk_mul_f32 v[88:89], v[72:73], v[72:73]\n\t"
        "v_pk_mul_f32 v[90:91], v[74:75], v[74:75]\n\t"
        "v_pk_mul_f32 v[92:93], v[76:77], v[76:77]\n\t"
        "v_pk_mul_f32 v[94:95], v[78:79], v[78:79]\n\t"
        "v_pk_add_f32 v[12:13], v[12:13], v[14:15]\n\t"
        "v_pk_add_f32 v[16:17], v[16:17], v[18:19]\n\t"
        "v_pk_add_f32 v[88:89], v[88:89], v[90:91]\n\t"
        "v_pk_add_f32 v[92:93], v[92:93], v[94:95]\n\t"
        "v_pk_add_f32 v[12:13], v[12:13], v[16:17]\n\t"
        "v_pk_add_f32 v[88:89], v[88:89], v[92:93]\n\t"
        "v_add_f32 v12, v12, v13\n\t"               // su lane-partial
        "v_add_f32 v16, v88, v89\n\t"               // sh lane-partial
        // wave reduce to lane 63 (DPP), su v12/tmp v30, sh v16/tmp v31
        "s_nop 1\n\t"
        "v_mov_b32_dpp v30, v12 row_shr:1 row_mask:0xf bank_mask:0xf\n\t"
        "v_mov_b32_dpp v31, v16 row_shr:1 row_mask:0xf bank_mask:0xf\n\t"
        "v_add_f32 v12, v12, v30\n\t"
        "v_add_f32 v16, v16, v31\n\t"
        "s_nop 0\n\t"
        "v_mov_b32_dpp v30, v12 row_shr:2 row_mask:0xf bank_mask:0xf\n\t"
        "v_mov_b32_dpp v31, v16 row_shr:2 row_mask:0xf bank_mask:0xf\n\t"
        "v_add_f32 v12, v12, v30\n\t"
        "v_add_f32 v16, v16, v31\n\t"
        "s_nop 0\n\t"
        "v_mov_b32_dpp v30, v12 row_shr:4 row_mask:0xf bank_mask:0xf\n\t"
        "v_mov_b32_dpp v31, v16 row_shr:4 row_mask:0xf bank_mask:0xf\n\t"
        "v_add_f32 v12, v12, v30\n\t"
        "v_add_f32 v16, v16, v31\n\t"
        "s_nop 0\n\t"
        "v_mov_b32_dpp v30, v12 row_shr:8 row_mask:0xf bank_mask:0xf\n\t"
        "v_mov_b32_dpp v31, v16 row_shr:8 row_mask:0xf bank_mask:0xf\n\t"
        "v_add_f32 v12, v12, v30\n\t"
        "v_add_f32 v16, v16, v31\n\t"
        "s_nop 0\n\t"
        "v_mov_b32_dpp v30, v12 row_bcast:15 row_mask:0xf bank_mask:0xf\n\t"
        "v_mov_b32_dpp v31, v16 row_bcast:15 row_mask:0xf bank_mask:0xf\n\t"
        "v_add_f32 v12, v12, v30\n\t"
        "v_add_f32 v16, v16, v31\n\t"
        "s_nop 0\n\t"
        "v_mov_b32_dpp v30, v12 row_bcast:31 row_mask:0xf bank_mask:0xf\n\t"
        "v_mov_b32_dpp v31, v16 row_bcast:31 row_mask:0xf bank_mask:0xf\n\t"
        "v_add_f32 v12, v12, v30\n\t"
        "v_add_f32 v16, v16, v31\n\t"
        "s_nop 1\n\t"
        // lane 63 publishes {su, sh}; barrier; issue combine reads
        "s_and_saveexec_b64 s[72:73], s[74:75]\n\t"
        "ds_write2_b32 v4, v12, v16 offset0:0 offset1:1\n\t"
        "s_mov_b64 exec, s[72:73]\n\t"
        "s_waitcnt lgkmcnt(0)\n\t"                  // ONLY the ds_write now
        "s_barrier\n\t"
        "ds_read_b128 v[32:35], v5\n\t"
        "ds_read_b128 v[36:39], v5 offset:16\n\t"
        // ---- ds_read shadow: everything not needing su/sh ----
        "v_mul_f32 v20, %[omq], v20\n\t"            // qlp_{t+1}
        "v_fmac_f32 v20, %[otq], v100\n\t"          //  (B.q)
        "v_mul_f32 v10, %[oq], v20\n\t"             // qsc pair
        "v_mov_b32 v11, v10\n\t"
        "v_pk_fma_f32 v[80:81], v[10:11], v[56:57], v[40:41]\n\t"  // hb_{t+1}
        "v_pk_fma_f32 v[82:83], v[10:11], v[58:59], v[42:43]\n\t"
        "v_pk_fma_f32 v[84:85], v[10:11], v[60:61], v[44:45]\n\t"
        "v_pk_fma_f32 v[86:87], v[10:11], v[62:63], v[46:47]\n\t"
        "v_mul_f32 v21, %[omy], v21\n\t"            // ylp_t
        "v_fmac_f32 v21, %[oty], v96\n\t"           //  (A.y)
        "v_add_f32 v1, v21, v101\n\t"               // pre = ylp_t + nz_{t+1}
        "v_mul_f32 v27, %[olr], v24\n\t"            // elpre = lr0*lrm
        "v_xor_b32 v4, 32, v4\n\t"                  // parity toggles
        "v_xor_b32 v5, 32, v5\n\t"
        "s_add_u32 s60, s60, 1\n\t"
        // ---- end shadow ----
        "s_waitcnt lgkmcnt(0)\n\t"                  // ONLY the 2 ds_reads
        "v_pk_add_f32 v[32:33], v[32:33], v[34:35]\n\t"
        "v_pk_add_f32 v[36:37], v[36:37], v[38:39]\n\t"
        "v_pk_add_f32 v[32:33], v[32:33], v[36:37]\n\t"   // su v32, sh v33
        // u ; x_{t+1} ; store (lane0 of every wave: identical value+addr)
        "v_mul_f32 v22, v25, v32\n\t"
        "v_fma_f32 v8, %[oum], v22, v1\n\t"         // x' = pre + (ufs-1)*u
        "v_mov_b32 v9, v8\n\t"
        "v_mul_f32 v30, %[oos], v22\n\t"
        "s_and_saveexec_b64 s[72:73], s[76:77]\n\t"
        "global_store_dword v6, v30, %[pou]\n\t"
        "s_mov_b64 exec, s[72:73]\n\t"
        "v_add_u32 v6, 0x800, v6\n\t"               // next row (+BS*4)
        // e, el, c
        "v_sub_f32 v23, v21, v22\n\t"               // e = ylp - u
        "v_mul_f32 v31, v27, v23\n\t"               // el = elpre*e
        "v_mul_f32 v28, v31, v26\n\t"               // c = el*rsp
        "v_mov_b32 v29, v28\n\t"
        // norm chain with v-update filling sqrt latency
        "v_mul_f32 v30, v31, v31\n\t"               // el^2
        "v_mul_f32 v30, v33, v30\n\t"               // *sh_t
        "v_add_f32 v30, 0x38d1b717, v30\n\t"        // + 1e-4f
        "v_sqrt_f32 v30, v30\n\t"
        "v_pk_fma_f32 v[64:65], v[28:29], v[72:73], v[64:65]\n\t"
        "v_pk_fma_f32 v[66:67], v[28:29], v[74:75], v[66:67]\n\t"
        "v_pk_fma_f32 v[68:69], v[28:29], v[76:77], v[68:69]\n\t"
        "v_pk_fma_f32 v[70:71], v[28:29], v[78:79], v[70:71]\n\t"
        "v_mul_f32 v30, %[ond], v30\n\t"
        "v_exp_f32 v30, v30\n\t"
        // scalar pipeline: wait until only the store is outstanding, rotate,
        // issue t+3 (loads are ~1 iteration old here -> no stall)
        "s_waitcnt vmcnt(1)\n\t"
        "v_mov_b32 v96, v99\n\t"  "v_mov_b32 v97, v100\n\t" "v_mov_b32 v98, v101\n\t"
        "v_mov_b32 v99, v102\n\t" "v_mov_b32 v100, v103\n\t" "v_mov_b32 v101, v104\n\t"
        "global_load_dword v102, v105, %[pys]\n\t"
        "global_load_dword v103, v105, %[pqs]\n\t"
        "global_load_dword v104, v106, %[pnz]\n\t"
        "v_add_u32 v105, 4, v105\n\t"
        "v_min_u32 v105, 0x3fc, v105\n\t"
        "v_add_u32 v106, 0x800, v106\n\t"
        "v_min_u32 v106, 0x7f800, v106\n\t"
        "v_mul_f32 v25, %[owd], v25\n\t"            // sp *= wd
        "v_mul_f32 v26, %[orw], v26\n\t"            // rsp *= rwd
        "v_mul_f32 v24, v24, v30\n\t"               // lrm *= exp2(...)
        "s_cmp_lt_u32 s60, 0x100\n\t"
        "s_cbranch_scc1 Lelbo4\n\t"
        "s_waitcnt vmcnt(0) lgkmcnt(0)\n\t"         // drain stores/loads
        :
        : [pys]"s"(ys), [pqs]"s"(qs), [pnz]"s"(nzp), [pou]"s"(out),
          [pzb]"s"(z_biases), [pwi]"s"(w_in), [pwq]"s"(w_inq),
          [vtid]"v"(tid), [ovo]"v"(ovo),
          [osg]"v"(sigb), [otq]"v"(tauq), [omq]"v"(omtq),
          [oty]"v"(tauy), [omy]"v"(omty), [oq]"v"(qscale),
          [oum]"v"(ufsm1), [olr]"v"(lr0), [owd]"v"(wd), [orw]"v"(rwd),
          [oos]"v"(oscale), [ond]"v"(nld2)
        : "memory", "scc", "vcc",
          "s60","s72","s73","s74","s75","s76","s77",
          "v1","v2","v3","v4","v5","v6","v7","v8","v9","v10","v11",
          "v12","v13","v14","v15","v16","v17","v18","v19","v20","v21",
          "v22","v23","v24","v25","v26","v27","v28","v29","v30","v31",
          "v32","v33","v34","v35","v36","v37","v38","v39","v40","v41",
          "v42","v43","v44","v45","v46","v47","v48","v49","v50","v51",
          "v52","v53","v54","v55","v56","v57","v58","v59","v60","v61",
          "v62","v63","v64","v65","v66","v67","v68","v69","v70","v71",
          "v72","v73","v74","v75","v76","v77","v78","v79","v80","v81",
          "v82","v83","v84","v85","v86","v87","v88","v89","v90","v91",
          "v92","v93","v94","v95","v96","v97","v98","v99","v100","v101",
          "v102","v103","v104","v105","v106"
    );
}

extern "C" void kernel_launch(void* const* d_in, const int* in_sizes, int n_in,
                              void* d_out, int out_size, void* d_ws, size_t ws_size,
                              hipStream_t stream) {
    (void)in_sizes; (void)n_in; (void)d_ws; (void)ws_size; (void)out_size;
    const float* noises   = (const float*)d_in[0];
    const float* ys       = (const float*)d_in[1];
    const float* qs       = (const float*)d_in[2];
    const float* z_biases = (const float*)d_in[3];
    const float* w_in     = (const float*)d_in[4];
    const float* w_inq    = (const float*)d_in[5];
    const float* llr      = (const float*)d_in[6];
    const float* llrd     = (const float*)d_in[7];
    const float* sigb     = (const float*)d_in[8];
    const float* oscale   = (const float*)d_in[9];
    const float* ufs      = (const float*)d_in[10];
    const float* lwd      = (const float*)d_in[11];
    const float* qscale   = (const float*)d_in[12];
    const float* tauq     = (const float*)d_in[13];
    const float* tauy     = (const float*)d_in[14];
    float* out = (float*)d_out;

    // 64 B dynamic LDS: keeps raw ds addresses 0..63 valid even if the
    // compiler were to drop the static red_lds allocation.
    hipLaunchKernelGGL(legacy_elbo_scan_kernel, dim3(BS), dim3(BLOCK), 64, stream,
                       noises, ys, qs, z_biases, w_in, w_inq,
                       llr, llrd, sigb, oscale, ufs, lwd, qscale, tauq, tauy,
                       out);
}